// Round 5
// baseline (83.807 us; speedup 1.0000x reference)
//
#include <hip/hip_runtime.h>
#include <cstdint>

// Ball query: B=8, N=4096, radius=0.2, nsample=32. Queries == sources.
// Output int32 (B,N,32): first 32 in-radius indices ascending, padded with
// the first match.
//
// NUMERICS (LOCKED, R8-verified absmax=0): expansion form f32,
//   sq  = (x*x + y*y) + z*z              -- plain, no FMA
//   dot = fma(qz,sz, fma(qy,sy, qx*sx))  -- FMA, K ascending
//   d2  = (sqq + sqs) - (dot + dot)
//   match = d2 < 0.04f
// Issued as v_pk_*_f32 (R15): each 32-bit half is the identical IEEE f32
// op in the identical order; subtract = pk_add with neg modifier. All in
// inline asm -- immune to -ffast-math/contract. DO NOT CHANGE.
//
// R16 perf theory: R12-R15 invariance matrix -- loads 3x, VALU 2x, load
// width, prefetch, queries/wave all changed NOTHING (79-80us); only LDS/
// barrier removal moved time (-4.6). Kernel ~37us vs ~10us issue model ->
// bound by the per-chunk dependent round-trip (loads -> d2 -> ballot -> F
// -> uniform branch gates next chunk), which single-wave prefetch cannot
// break. The ONE untested axis: waves/SIMD (all prior: 128-thr blocks,
// ~100 VGPR, ~4 waves/SIMD). R16: ONE query per wave -- 32768 independent
// waves, ~40 VGPR, __launch_bounds__(256,8) -> 8 waves/SIMD = 2x latency
// hiding; exact per-query scan depth (no max-coupling, no skip logic);
// perfect tail balance. If this is ALSO flat, the residual is harness
// floor (256MiB poison fill 41us + reset dispatch train) and the kernel
// is at its ballot-formulation floor -> declare roofline.

#define BQ_N    4096
#define BQ_B    8
#define BQ_NS   32
#define BQ_R2   0.04f
#define BQ_NC   16    // chunks of 256 points (4 rounds of 64)

typedef float v2f __attribute__((ext_vector_type(2)));

// Scalar sq for the query point (original LOCKED asm).
__device__ __forceinline__ float sq_plain(float x, float y, float z) {
    float r, t;
    asm("v_mul_f32 %0, %2, %2\n\t"
        "v_mul_f32 %1, %3, %3\n\t"
        "v_add_f32 %0, %0, %1\n\t"
        "v_mul_f32 %1, %4, %4\n\t"
        "v_add_f32 %0, %0, %1"
        : "=&v"(r), "=&v"(t)
        : "v"(x), "v"(y), "v"(z));
    return r;
}

// Packed sq for two scan points: per-half identical op order
// (x*x + y*y) + z*z, plain mul/add.
__device__ __forceinline__ v2f sq2_plain(v2f x, v2f y, v2f z) {
    v2f r, t;
    asm("v_pk_mul_f32 %0, %2, %2 op_sel:[0,0] op_sel_hi:[1,1]\n\t"
        "v_pk_mul_f32 %1, %3, %3 op_sel:[0,0] op_sel_hi:[1,1]\n\t"
        "v_pk_add_f32 %0, %0, %1 op_sel:[0,0] op_sel_hi:[1,1]\n\t"
        "v_pk_mul_f32 %1, %4, %4 op_sel:[0,0] op_sel_hi:[1,1]\n\t"
        "v_pk_add_f32 %0, %0, %1 op_sel:[0,0] op_sel_hi:[1,1]"
        : "=&v"(r), "=&v"(t)
        : "v"(x), "v"(y), "v"(z));
    return r;
}

// Packed d2 for two consecutive rounds vs one query.
// qa = {qx, qy}, qb = {qz, sqq}; s* = {point_k comp, point_{k+1} comp}.
// Per half:  dot = fma(qz,sz, fma(qy,sy, qx*sx));
//            d2  = (sqq + sqs) - (dot + dot)     [sub via neg modifier]
__device__ __forceinline__ v2f d2_pk(v2f qa, v2f qb, v2f sx, v2f sy, v2f sz,
                                     v2f sq2) {
    v2f r, t;
    asm("v_pk_mul_f32 %0, %2, %4 op_sel:[0,0] op_sel_hi:[0,1]\n\t"
        "v_pk_fma_f32 %0, %2, %5, %0 op_sel:[1,0,0] op_sel_hi:[1,1,1]\n\t"
        "v_pk_fma_f32 %0, %3, %6, %0 op_sel:[0,0,0] op_sel_hi:[0,1,1]\n\t"
        "v_pk_add_f32 %0, %0, %0 op_sel:[0,0] op_sel_hi:[1,1]\n\t"
        "v_pk_add_f32 %1, %3, %7 op_sel:[1,0] op_sel_hi:[1,1]\n\t"
        "v_pk_add_f32 %0, %1, %0 op_sel:[0,0] op_sel_hi:[1,1] neg_lo:[0,1] neg_hi:[0,1]"
        : "=&v"(r), "=&v"(t)
        : "v"(qa), "v"(qb), "v"(sx), "v"(sy), "v"(sz), "v"(sq2));
    return r;
}

// Two rounds (k, k+1): ballots + lane==k capture of word and exclusive
// prefix. bal/f are wave-uniform; captures are cndmask/exec-masked movs.
__device__ __forceinline__ void proc_pair(v2f qa, v2f qb, v2f sx, v2f sy,
                                          v2f sz, v2f sq2, int lane, int k,
                                          uint32_t& wlo, uint32_t& whi,
                                          int& p, int& f) {
    const v2f d2 = d2_pk(qa, qb, sx, sy, sz, sq2);
    const uint64_t b0 = __ballot(d2[0] < BQ_R2);        // round k
    if (lane == k)     { wlo = (uint32_t)b0; whi = (uint32_t)(b0 >> 32); p = f; }
    f += (int)__popcll(b0);
    const uint64_t b1 = __ballot(d2[1] < BQ_R2);        // round k+1
    if (lane == k + 1) { wlo = (uint32_t)b1; whi = (uint32_t)(b1 >> 32); p = f; }
    f += (int)__popcll(b1);
}

// Prefix-free emit: lane k holds round-k word and wpre (= matches before
// round k, captured during scan). Pure stores; padding only when total<32.
__device__ __forceinline__ void emit_query(int* __restrict__ orow, int lane,
                                           uint32_t wlo, uint32_t whi,
                                           int wpre, int total)
{
    const uint64_t word = ((uint64_t)whi << 32) | wlo;
    uint64_t w = word;
    int pos = wpre;                      // >=32 for overshoot rounds -> skipped
    while (w != 0ull && pos < BQ_NS) {
        const int bit = __builtin_ctzll(w);
        orow[pos] = (lane << 6) + bit;   // lane == round k; ascending order
        w &= (w - 1);
        ++pos;
    }
    if (total < BQ_NS) {                 // rare (queries with <32 neighbors)
        int first;
        const uint64_t nz = __ballot(word != 0ull);
        if (nz == 0ull) {
            first = BQ_N;   // defensive; self-match (|d2|<=2e-7) makes this unreachable
        } else {
            const int fl = __builtin_ctzll(nz);
            const uint64_t fw = __shfl(word, fl);
            first = (fl << 6) + __builtin_ctzll(fw);
        }
        if (lane >= total && lane < BQ_NS) orow[lane] = first;
    }
}

__global__ __launch_bounds__(256, 8)
void ball_query_kernel(const float* __restrict__ xyz, int* __restrict__ out)
{
    const int gw   = (blockIdx.x << 2) + (threadIdx.x >> 6); // wave id 0..32767
    const int b    = gw >> 12;                               // 4096 q / batch
    const int m    = gw & (BQ_N - 1);                        // this wave's query
    const int lane = threadIdx.x & 63;
    const float* __restrict__ src = xyz + (size_t)b * BQ_N * 3;

    // The wave's single query as packed pairs {qx,qy}, {qz,sqq}.
    const float qx = src[3 * m + 0];
    const float qy = src[3 * m + 1];
    const float qz = src[3 * m + 2];
    v2f Qa, Qb;
    Qa[0] = qx; Qa[1] = qy;
    Qb[0] = qz; Qb[1] = sq_plain(qx, qy, qz);

    uint32_t wlo = 0, whi = 0;
    int p = 0, f = 0;

    // Stepping lane-pointer: chunk c round u component w lives at
    // lp[u*192 + w]; all 12 offsets are compile-time immediates (<= 2312B).
    const float* lp = src + lane * 3;

    for (int c = 0; c < BQ_NC; ++c) {
        // Load chunk: rounds (0,1) -> lo/hi of *01, rounds (2,3) -> *23.
        v2f X01, Y01, Z01, X23, Y23, Z23;
        X01[0] = lp[  0]; X01[1] = lp[192];
        Y01[0] = lp[  1]; Y01[1] = lp[193];
        Z01[0] = lp[  2]; Z01[1] = lp[194];
        X23[0] = lp[384]; X23[1] = lp[576];
        Y23[0] = lp[385]; Y23[1] = lp[577];
        Z23[0] = lp[386]; Z23[1] = lp[578];
        lp += 768;

        const v2f SQ01 = sq2_plain(X01, Y01, Z01);
        const v2f SQ23 = sq2_plain(X23, Y23, Z23);

        const int k0 = c << 2;
        proc_pair(Qa, Qb, X01, Y01, Z01, SQ01, lane, k0,     wlo, whi, p, f);
        proc_pair(Qa, Qb, X23, Y23, Z23, SQ23, lane, k0 + 2, wlo, whi, p, f);

        if (f >= BQ_NS) break;           // exact per-query early exit
    }

    emit_query(out + (size_t)gw * BQ_NS, lane, wlo, whi, p, f);
}

extern "C" void kernel_launch(void* const* d_in, const int* in_sizes, int n_in,
                              void* d_out, int out_size, void* d_ws, size_t ws_size,
                              hipStream_t stream)
{
    const float* xyz = (const float*)d_in[0];   // (8, 4096, 3) f32; d_in[1] unused
    int* out = (int*)d_out;                     // (8, 4096, 32) int32
    hipLaunchKernelGGL(ball_query_kernel, dim3(8192), dim3(256), 0, stream,
                       xyz, out);
}

// Round 6
// 79.260 us; speedup vs baseline: 1.0574x; 1.0574x over previous
//
#include <hip/hip_runtime.h>
#include <cstdint>

// Ball query: B=8, N=4096, radius=0.2, nsample=32. Queries == sources.
// Output int32 (B,N,32): first 32 in-radius indices ascending, padded with
// the first match.
//
// NUMERICS (LOCKED, R8-verified absmax=0): expansion form f32,
//   sq  = (x*x + y*y) + z*z              -- plain, no FMA
//   dot = fma(qz,sz, fma(qy,sy, qx*sx))  -- FMA, K ascending
//   d2  = (sqq + sqs) - (dot + dot)
//   match = d2 < 0.04f
// All in inline asm -- immune to -ffast-math/contract. DO NOT CHANGE.
//
// R17 = revert to R12 (measured best, 79.1us). FINAL-CANDIDATE.
//
// Floor analysis (R12-R16): five structurally different kernels (loads
// 3x, VALU 2x, q/wave 1-8, occupancy 4-8 waves/SIMD, LDS on/off) all land
// at 79.1-83.8us. Conservation arithmetic: 37us of "kernel" would mean
// 93G issue-slots for ~10M inst-cycles of work (0.01%), and even a fully
// serialized per-chunk L2-latency chain caps at ~7us -- so the kernel
// CANNOT be ~37us. The measurement responds to ADDED work (+1 dispatch =
// +1.9us R13; +2.7x loads = +4.1us R16) but never to removed work ->
// kernel is ~5-10us, below the floor: harness poison fill (41us at 81-84%
// HBM peak = at the bandwidth roofline, harness-owned) + reset dispatch
// train + graph overhead ~= 79us. R12's structure is the least-work member
// of the 79us cluster -> reverted verbatim.

#define BQ_N    4096
#define BQ_B    8
#define BQ_NS   32
#define BQ_R2   0.04f
#define BQ_NC   16    // chunks of 256 points (4 rounds of 64)

__device__ __forceinline__ float sq_plain(float x, float y, float z) {
    float r, t;
    asm("v_mul_f32 %0, %2, %2\n\t"
        "v_mul_f32 %1, %3, %3\n\t"
        "v_add_f32 %0, %0, %1\n\t"
        "v_mul_f32 %1, %4, %4\n\t"
        "v_add_f32 %0, %0, %1"
        : "=&v"(r), "=&v"(t)
        : "v"(x), "v"(y), "v"(z));
    return r;
}

__device__ __forceinline__ float d2_mixed(float qx, float qy, float qz, float sqq,
                                          float sx, float sy, float sz, float sqs) {
    float r, t;
    asm("v_mul_f32 %0, %2, %5\n\t"     // qx*sx
        "v_fma_f32 %0, %3, %6, %0\n\t" // + qy*sy (fused)
        "v_fma_f32 %0, %4, %7, %0\n\t" // + qz*sz (fused) = dot
        "v_add_f32 %0, %0, %0\n\t"     // 2*dot (exact)
        "v_add_f32 %1, %8, %9\n\t"     // sqq + sqs
        "v_sub_f32 %0, %1, %0"         // d2
        : "=&v"(r), "=&v"(t)
        : "v"(qx), "v"(qy), "v"(qz), "v"(sx), "v"(sy), "v"(sz),
          "v"(sqq), "v"(sqs));
    return r;
}

// One 4-round chunk (256 points) for a single query, points straight from
// global (L2-hit: 48KB/batch is L2-resident). Captures per-round ballot word
// AND the exclusive prefix count (wpre) at lane==k -- emit needs no scan.
__device__ __forceinline__ void scan1g(const float* __restrict__ src, int lane,
                                       const float4& q, int c,
                                       uint64_t& word, int& wpre, int& found) {
    float X[4], Y[4], Z[4];
    #pragma unroll
    for (int u = 0; u < 4; ++u) {           // 4 independent 768B/wave loads
        const int k = (c << 2) + u;
        const float* ptr = src + (size_t)(((k << 6) + lane) * 3);
        X[u] = ptr[0]; Y[u] = ptr[1]; Z[u] = ptr[2];
    }
    #pragma unroll
    for (int u = 0; u < 4; ++u) {
        const int k = (c << 2) + u;
        const float sqs = sq_plain(X[u], Y[u], Z[u]);
        const float d2  = d2_mixed(q.x, q.y, q.z, q.w, X[u], Y[u], Z[u], sqs);
        const uint64_t bal = __ballot(d2 < BQ_R2);
        if (lane == k) { word = bal; wpre = found; }
        found += (int)__popcll(bal);
    }
}

// Dual-query cascade over chunk range [c0, c1): both share each global load
// and the shared sq; after the OR-break, singles finish independently.
__device__ __forceinline__ void scan2g(const float* __restrict__ src, int lane,
                                       const float4& q0, const float4& q1,
                                       int c0, int c1,
                                       uint64_t& w0, uint64_t& w1,
                                       int& p0, int& p1, int& f0, int& f1) {
    int c = c0;
    while (c < c1) {
        float X[4], Y[4], Z[4];
        #pragma unroll
        for (int u = 0; u < 4; ++u) {
            const int k = (c << 2) + u;
            const float* ptr = src + (size_t)(((k << 6) + lane) * 3);
            X[u] = ptr[0]; Y[u] = ptr[1]; Z[u] = ptr[2];
        }
        #pragma unroll
        for (int u = 0; u < 4; ++u) {
            const int k = (c << 2) + u;
            const float sqs = sq_plain(X[u], Y[u], Z[u]);
            const float d20 = d2_mixed(q0.x, q0.y, q0.z, q0.w,
                                       X[u], Y[u], Z[u], sqs);
            const float d21 = d2_mixed(q1.x, q1.y, q1.z, q1.w,
                                       X[u], Y[u], Z[u], sqs);
            const uint64_t b0 = __ballot(d20 < BQ_R2);
            const uint64_t b1 = __ballot(d21 < BQ_R2);
            if (lane == k) { w0 = b0; w1 = b1; p0 = f0; p1 = f1; }
            f0 += (int)__popcll(b0);
            f1 += (int)__popcll(b1);
        }
        ++c;
        if (f0 >= BQ_NS || f1 >= BQ_NS) break;   // uniform
    }
    for (int ca = c; ca < c1 && f0 < BQ_NS; ++ca) scan1g(src, lane, q0, ca, w0, p0, f0);
    for (int cb = c; cb < c1 && f1 < BQ_NS; ++cb) scan1g(src, lane, q1, cb, w1, p1, f1);
}

// Prefix-free emit: lane k holds round-k word and wpre (= matches before
// round k, captured during scan). Pure stores; padding only when total<32.
__device__ __forceinline__ void emit_query(int* __restrict__ orow, int lane,
                                           uint64_t word, int wpre, int total)
{
    uint64_t w = word;
    int pos = wpre;                      // >=32 for overshoot rounds -> skipped
    while (w != 0ull && pos < BQ_NS) {
        const int bit = __builtin_ctzll(w);
        orow[pos] = (lane << 6) + bit;   // lane == round k; ascending order
        w &= (w - 1);
        ++pos;
    }
    if (total < BQ_NS) {                 // rare (queries with <32 neighbors)
        int first;
        const uint64_t nz = __ballot(word != 0ull);
        if (nz == 0ull) {
            first = BQ_N;   // defensive; self-match (|d2|<=2e-7) makes this unreachable
        } else {
            const int fl = __builtin_ctzll(nz);
            const uint64_t fw = __shfl(word, fl);
            first = (fl << 6) + __builtin_ctzll(fw);
        }
        if (lane >= total && lane < BQ_NS) orow[lane] = first;
    }
}

__global__ __launch_bounds__(128, 4)
void ball_query_kernel(const float* __restrict__ xyz, int* __restrict__ out)
{
    const int b     = blockIdx.x >> 9;          // 512 blocks per batch
    const int qbase = (blockIdx.x & 511) << 3;  // 8 queries per block
    const int lane  = threadIdx.x & 63;
    const int wid   = threadIdx.x >> 6;         // 2 independent waves/block
    const float* __restrict__ src = xyz + (size_t)b * BQ_N * 3;
    int* __restrict__ outb = out + (size_t)(b * BQ_N) * BQ_NS;

    // Wave's 4 query points (wave-uniform addresses -> scalar/L2).
    float4 Q[4];
    #pragma unroll
    for (int j = 0; j < 4; ++j) {
        const int m = qbase + (wid << 2) + j;
        const float x = src[3 * m + 0];
        const float y = src[3 * m + 1];
        const float z = src[3 * m + 2];
        Q[j] = make_float4(x, y, z, sq_plain(x, y, z));
    }

    uint64_t W[4] = {0, 0, 0, 0};
    int      P[4] = {0, 0, 0, 0};
    int      F[4] = {0, 0, 0, 0};

    // Two cascades over all 16 chunks (4096 points), no phases, no barriers.
    scan2g(src, lane, Q[0], Q[1], 0, 16, W[0], W[1], P[0], P[1], F[0], F[1]);
    scan2g(src, lane, Q[2], Q[3], 0, 16, W[2], W[3], P[2], P[3], F[2], F[3]);

    #pragma unroll
    for (int j = 0; j < 4; ++j) {
        const int m = qbase + (wid << 2) + j;
        emit_query(outb + (size_t)m * BQ_NS, lane, W[j], P[j], F[j]);
    }
}

extern "C" void kernel_launch(void* const* d_in, const int* in_sizes, int n_in,
                              void* d_out, int out_size, void* d_ws, size_t ws_size,
                              hipStream_t stream)
{
    const float* xyz = (const float*)d_in[0];   // (8, 4096, 3) f32; d_in[1] unused
    int* out = (int*)d_out;                     // (8, 4096, 32) int32
    hipLaunchKernelGGL(ball_query_kernel, dim3(4096), dim3(128), 0, stream,
                       xyz, out);
}